// Round 1
// baseline (290.151 us; speedup 1.0000x reference)
//
#include <hip/hip_runtime.h>

#define INF 1e10f
#define EPSV 1e-5f
#define NB 2
#define NN 512
#define NF 64
#define NH 64
#define NCC 32
#define NRBF 50

__device__ __forceinline__ float frcp(float x){ return __builtin_amdgcn_rcpf(x); }
__device__ __forceinline__ float silu_f(float x){ return x * frcp(1.f + __expf(-x)); }
__device__ __forceinline__ float tanh_f(float x){
  float cx = fminf(fmaxf(x, -15.f), 15.f);
  float t = __expf(2.f * cx);
  return (t - 1.f) * frcp(t + 1.f);
}

__device__ __forceinline__ float wredMax(float v){
  v = fmaxf(v, __shfl_down(v, 32)); v = fmaxf(v, __shfl_down(v, 16));
  v = fmaxf(v, __shfl_down(v, 8));  v = fmaxf(v, __shfl_down(v, 4));
  v = fmaxf(v, __shfl_down(v, 2));  v = fmaxf(v, __shfl_down(v, 1));
  return v;
}
__device__ __forceinline__ float wredSum(float v){
  v += __shfl_down(v, 32); v += __shfl_down(v, 16); v += __shfl_down(v, 8);
  v += __shfl_down(v, 4);  v += __shfl_down(v, 2);  v += __shfl_down(v, 1);
  return v;
}
__device__ __forceinline__ float bredMax(float v, float* red, int tid){
  float w = wredMax(v);
  __syncthreads();
  if ((tid & 63) == 0) red[tid >> 6] = w;
  __syncthreads();
  return fmaxf(fmaxf(red[0], red[1]), fmaxf(red[2], red[3]));
}
__device__ __forceinline__ float bredSum(float v, float* red, int tid){
  float w = wredSum(v);
  __syncthreads();
  if ((tid & 63) == 0) red[tid >> 6] = w;
  __syncthreads();
  return (red[0] + red[1]) + (red[2] + red[3]);
}

// ---------------- Kernel A: per-node projections --------------------------
// u[n]=h[n]@W_dh[0:F], v[n]=h[n]@W_dh[F:2F], s1/s2 = h@W_sa halves,
// e1/e2 = h@W_ew[0:F]/[F:2F]
__global__ void kA(const float* __restrict__ h, const float* __restrict__ Wdh,
                   const float* __restrict__ Wew, const float* __restrict__ Wsa,
                   float* __restrict__ u, float* __restrict__ v,
                   float* __restrict__ e1, float* __restrict__ e2,
                   float* __restrict__ s1, float* __restrict__ s2){
  const int node = blockIdx.x;
  const int l = threadIdx.x;
  __shared__ float sh[NF];
  sh[l] = h[node * NF + l];
  __syncthreads();
  float ua = 0.f, va = 0.f;
  #pragma unroll
  for (int f = 0; f < NF; ++f){
    float hv = sh[f];
    ua = fmaf(hv, Wdh[f * NH + l], ua);
    va = fmaf(hv, Wdh[(NF + f) * NH + l], va);
  }
  u[node * NH + l] = ua;
  v[node * NH + l] = va;
  const int nc = l & 31;
  const int roff = (l >> 5) * NF;
  float ea = 0.f;
  #pragma unroll
  for (int f = 0; f < NF; ++f) ea = fmaf(sh[f], Wew[(roff + f) * NCC + nc], ea);
  if (l < 32) e1[node * NCC + nc] = ea; else e2[node * NCC + nc] = ea;
  if (l < 2){
    const float* wp = Wsa + l * NF;
    float s = 0.f;
    #pragma unroll
    for (int f = 0; f < NF; ++f) s = fmaf(sh[f], wp[f], s);
    if (l == 0) s1[node] = s; else s2[node] = s;
  }
}

// ---------------- Kernel B: per-(b,i) edge pass ---------------------------
__global__ __launch_bounds__(256, 2) void kB(
    const float* __restrict__ x, const float* __restrict__ mask, const float* __restrict__ mu,
    const float* __restrict__ Wf_g, const float* __restrict__ bf_g, const float* __restrict__ bdh_g,
    const float* __restrict__ Wew_g, const float* __restrict__ bew_g,
    const float* __restrict__ Wcm1_g, const float* __restrict__ bcm1_g,
    const float* __restrict__ Wcm2_g, const float* __restrict__ bcm2_g,
    const float* __restrict__ u_g, const float* __restrict__ v_g,
    const float* __restrict__ s1_g, const float* __restrict__ s2_g,
    const float* __restrict__ e1_g, const float* __restrict__ e2_g,
    float* __restrict__ hga_g, float* __restrict__ attn_g, float* __restrict__ out)
{
  const int bid = blockIdx.x;
  const int b = bid >> 9;
  const int i = bid & (NN - 1);
  const int tid = threadIdx.x;
  const int lane = tid & 63;
  const int wave = tid >> 6;
  const int base = b * NN;

  __shared__ __align__(16) float4 s_geo[NN];   // d0,d1,d2,norm
  __shared__ __align__(8)  float2 s_mt[NN];    // mask, total
  __shared__ __align__(16) float s_f[4][64];   // per-wave filtered broadcast
  __shared__ float s_att[4][96];
  __shared__ float s_agg[4][64];
  __shared__ float s_xw[4][3];
  __shared__ float s_red[4];

  const float xi0 = x[(base + i) * 3 + 0];
  const float xi1 = x[(base + i) * 3 + 1];
  const float xi2 = x[(base + i) * 3 + 2];
  const float s2i = s2_g[base + i];

  // ---- pass 1: logits + 3-stage softmax chain (thread-per-j, 2 j each) ----
  float aj[2], sl[2], mj[2];
  #pragma unroll
  for (int q = 0; q < 2; ++q){
    const int j = tid + q * 256;
    float d0 = x[(base + j) * 3 + 0] - xi0;
    float d1 = x[(base + j) * 3 + 1] - xi1;
    float d2 = x[(base + j) * 3 + 2] - xi2;
    float nsq = d0 * d0 + d1 * d1 + d2 * d2;
    float norm = sqrtf(fmaxf(nsq, 0.f) + EPSV);
    float m = mask[(base + i) * NN + j];
    float eye = (j == i) ? 1.f : 0.f;
    float a = -(norm + eye * INF + (1.f - m) * INF);          // spatial logit
    float sp = s1_g[base + j] + s2i;
    float sv = silu_f(sp) - eye * INF + (m - 1.f) * INF;       // sem logit
    s_geo[j] = make_float4(d0, d1, d2, norm);
    s_mt[j].x = m;
    aj[q] = a; sl[q] = sv; mj[q] = m;
  }
  float M1 = bredMax(fmaxf(aj[0], aj[1]), s_red, tid);
  float S1 = bredSum(__expf(aj[0] - M1) + __expf(aj[1] - M1), s_red, tid);
  float M2 = bredMax(fmaxf(sl[0], sl[1]), s_red, tid);
  float S2 = bredSum(__expf(sl[0] - M2) + __expf(sl[1] - M2), s_red, tid);
  const float iS1 = 1.f / S1, iS2 = 1.f / S2;
  float p[2];
  #pragma unroll
  for (int q = 0; q < 2; ++q)
    p[q] = (__expf(sl[q] - M2) * iS2) * (__expf(aj[q] - M1) * iS1) + (mj[q] - 1.f) * INF;
  float M3 = bredMax(fmaxf(p[0], p[1]), s_red, tid);
  float S3 = bredSum(__expf(p[0] - M3) + __expf(p[1] - M3), s_red, tid);
  const float iS3 = 1.f / S3;
  s_mt[tid].y       = __expf(p[0] - M3) * iS3;
  s_mt[tid + 256].y = __expf(p[1] - M3) * iS3;
  __syncthreads();

  // ---- pass 2 prologue: per-lane register-resident weight columns ----
  const float muv = (lane < NRBF) ? mu[lane] : 0.f;
  float Wfr[NRBF];
  #pragma unroll
  for (int r = 0; r < NRBF; ++r) Wfr[r] = Wf_g[r * NH + lane];
  float Wc1[NH];
  #pragma unroll
  for (int t = 0; t < NH; ++t) Wc1[t] = Wcm1_g[t * NH + lane];
  const int nc = lane & 31;
  const int hh0 = (lane >> 5) * 32;          // which h-half this lane dots for w
  float We3[32];
  #pragma unroll
  for (int t = 0; t < 32; ++t) We3[t] = Wew_g[(2 * NF + hh0 + t) * NCC + nc];
  const float ewpb = e1_g ? (e2_g[(base + i) * NCC + nc] + bew_g[nc]) : 0.f;
  const float viv  = v_g[(base + i) * NH + lane];
  const float bdhv = bdh_g[lane];
  const float bfv  = bf_g[lane];
  const float bc1v = bcm1_g[lane];
  const float wc2v = Wcm2_g[lane];
  const float bc2v = bcm2_g[0];

  float agg = 0.f, at0 = 0.f, at1 = 0.f, at2 = 0.f, xa0 = 0.f, xa1 = 0.f, xa2 = 0.f;
  const float4* f4 = reinterpret_cast<const float4*>(&s_f[wave][0]);

  // ---- pass 2: channel-per-lane edge loop, 128 j per wave ----
  for (int j = wave * 128; j < wave * 128 + 128; ++j){
    float4 geo = s_geo[j];
    float2 mt  = s_mt[j];
    float norm = geo.w, m = mt.x, tot = mt.y;
    float uj  = u_g[(base + j) * NH + lane];
    float e1v = e1_g[(base + j) * NCC + nc];
    // RBF basis: lane r computes e_r, broadcast by readlane
    float dm = norm - muv;
    float e = __expf(-10.f * dm * dm);
    float filt = bfv;
    #pragma unroll
    for (int r = 0; r < NRBF; ++r){
      float er = __uint_as_float(__builtin_amdgcn_readlane(__float_as_uint(e), r));
      filt = fmaf(er, Wfr[r], filt);
    }
    float fH = (uj + viv + bdhv) * filt;     // filtered[h]
    s_f[wave][lane] = fH;
    __builtin_amdgcn_wave_barrier();
    asm volatile("" ::: "memory");
    float he = fH * m;                        // h_e[h]
    agg = fmaf(tot, he, agg);                 // h_e_agg accumulation
    // cm dot: t_k = sum_h f[h]*W_cm1[h][k]
    float cm = 0.f;
    #pragma unroll
    for (int c = 0; c < 16; ++c){
      float4 fv = f4[c];
      cm = fmaf(fv.x, Wc1[4 * c + 0], cm);
      cm = fmaf(fv.y, Wc1[4 * c + 1], cm);
      cm = fmaf(fv.z, Wc1[4 * c + 2], cm);
      cm = fmaf(fv.w, Wc1[4 * c + 3], cm);
    }
    // w dot: half-range per lane, combined across halves
    float wacc = 0.f;
    #pragma unroll
    for (int c = 0; c < 8; ++c){
      float4 fv = f4[(hh0 >> 2) + c];
      wacc = fmaf(fv.x, We3[4 * c + 0], wacc);
      wacc = fmaf(fv.y, We3[4 * c + 1], wacc);
      wacc = fmaf(fv.z, We3[4 * c + 2], wacc);
      wacc = fmaf(fv.w, We3[4 * c + 3], wacc);
    }
    wacc += __shfl_xor(wacc, 32);
    float wv = tanh_f(ewpb + e1v + wacc);
    float inv = frcp(norm * norm + EPSV);
    float c0 = geo.x * inv * m, c1 = geo.y * inv * m, c2 = geo.z * inv * m;
    at0 = fmaf(wv, c0, at0); at1 = fmaf(wv, c1, at1); at2 = fmaf(wv, c2, at2);
    // coordinate-MLP scalar: silu(m*cm + b) . W_cm2  (wave butterfly dot)
    float tk = silu_f(fmaf(m, cm, bc1v));
    float pv = tk * wc2v;
    pv += __shfl_xor(pv, 1);  pv += __shfl_xor(pv, 2);  pv += __shfl_xor(pv, 4);
    pv += __shfl_xor(pv, 8);  pv += __shfl_xor(pv, 16); pv += __shfl_xor(pv, 32);
    float hE = (pv + bc2v) * m;
    xa0 = fmaf(geo.x, hE, xa0); xa1 = fmaf(geo.y, hE, xa1); xa2 = fmaf(geo.z, hE, xa2);
  }

  // ---- epilogue: cross-wave combine ----
  __syncthreads();
  if (lane < 32){
    s_att[wave][lane * 3 + 0] = at0;
    s_att[wave][lane * 3 + 1] = at1;
    s_att[wave][lane * 3 + 2] = at2;
  }
  s_agg[wave][lane] = agg;
  if (lane == 0){ s_xw[wave][0] = xa0; s_xw[wave][1] = xa1; s_xw[wave][2] = xa2; }
  __syncthreads();
  if (tid < 96){
    float a = s_att[0][tid] + s_att[1][tid] + s_att[2][tid] + s_att[3][tid];
    s_att[0][tid] = a;
  }
  if (tid >= 128 && tid < 192){
    int hh = tid - 128;
    hga_g[(base + i) * NH + hh] = s_agg[0][hh] + s_agg[1][hh] + s_agg[2][hh] + s_agg[3][hh];
  }
  if (tid >= 224 && tid < 227){
    int d = tid - 224;
    out[NB * NN * NH + (base + i) * 3 + d] =
        s_xw[0][d] + s_xw[1][d] + s_xw[2][d] + s_xw[3][d] + x[(base + i) * 3 + d];
  }
  __syncthreads();
  if (tid < 32){
    float a0 = s_att[0][tid * 3 + 0], a1 = s_att[0][tid * 3 + 1], a2 = s_att[0][tid * 3 + 2];
    attn_g[(base + i) * NCC + tid] = sqrtf(fmaxf(a0 * a0 + a1 * a1 + a2 * a2, 0.f) + EPSV);
  }
}

// ---------------- Kernel C: per-node tail MLPs ----------------------------
__global__ void kC(const float* __restrict__ h, const float* __restrict__ attn,
                   const float* __restrict__ hga,
                   const float* __restrict__ Wpn1, const float* __restrict__ bpn1,
                   const float* __restrict__ Wpn2, const float* __restrict__ bpn2,
                   const float* __restrict__ Wnm1, const float* __restrict__ bnm1,
                   const float* __restrict__ Wnm2, const float* __restrict__ bnm2,
                   float* __restrict__ out)
{
  const int node = blockIdx.x;
  const int k = threadIdx.x;
  __shared__ float sa[NCC], shh[NF], sg[NH], sq[NH], se[NH], sr[NH];
  if (k < NCC) sa[k] = attn[node * NCC + k];
  shh[k] = h[node * NF + k];
  sg[k]  = hga[node * NH + k];
  __syncthreads();
  float acc = bpn1[k];
  #pragma unroll
  for (int t = 0; t < NCC; ++t) acc = fmaf(sa[t], Wpn1[t * NH + k], acc);
  sq[k] = silu_f(acc);
  __syncthreads();
  acc = bpn2[k];
  #pragma unroll
  for (int t = 0; t < NH; ++t) acc = fmaf(sq[t], Wpn2[t * NH + k], acc);
  se[k] = acc;                                  // emb
  __syncthreads();
  acc = bnm1[k];
  #pragma unroll
  for (int t = 0; t < NF; ++t) acc = fmaf(shh[t], Wnm1[t * NH + k], acc);
  #pragma unroll
  for (int t = 0; t < NH; ++t) acc = fmaf(sg[t],  Wnm1[(NF + t) * NH + k], acc);
  #pragma unroll
  for (int t = 0; t < NH; ++t) acc = fmaf(se[t],  Wnm1[(NF + NH + t) * NH + k], acc);
  sr[k] = silu_f(acc);
  __syncthreads();
  acc = bnm2[k];
  #pragma unroll
  for (int t = 0; t < NH; ++t) acc = fmaf(sr[t], Wnm2[t * NH + k], acc);
  out[node * NH + k] = acc;
}

extern "C" void kernel_launch(void* const* d_in, const int* in_sizes, int n_in,
                              void* d_out, int out_size, void* d_ws, size_t ws_size,
                              hipStream_t stream){
  const float* h    = (const float*)d_in[0];
  const float* x    = (const float*)d_in[1];
  const float* mask = (const float*)d_in[2];
  const float* Wdh  = (const float*)d_in[3];
  const float* bdh  = (const float*)d_in[4];
  const float* mu   = (const float*)d_in[5];
  const float* Wf   = (const float*)d_in[6];
  const float* bf   = (const float*)d_in[7];
  const float* Wsa  = (const float*)d_in[8];
  const float* Wew  = (const float*)d_in[9];
  const float* bew  = (const float*)d_in[10];
  const float* Wpn1 = (const float*)d_in[11];
  const float* bpn1 = (const float*)d_in[12];
  const float* Wpn2 = (const float*)d_in[13];
  const float* bpn2 = (const float*)d_in[14];
  const float* Wnm1 = (const float*)d_in[15];
  const float* bnm1 = (const float*)d_in[16];
  const float* Wnm2 = (const float*)d_in[17];
  const float* bnm2 = (const float*)d_in[18];
  const float* Wcm1 = (const float*)d_in[19];
  const float* bcm1 = (const float*)d_in[20];
  const float* Wcm2 = (const float*)d_in[21];
  const float* bcm2 = (const float*)d_in[22];
  float* out = (float*)d_out;
  float* ws  = (float*)d_ws;

  float* u    = ws;            // [B*N,64]
  float* v    = u   + 65536;   // [B*N,64]
  float* s1   = v   + 65536;   // [B*N]
  float* s2   = s1  + 1024;    // [B*N]
  float* e1   = s2  + 1024;    // [B*N,32]
  float* e2   = e1  + 32768;   // [B*N,32]
  float* hga  = e2  + 32768;   // [B*N,64]
  float* attn = hga + 65536;   // [B*N,32]

  hipLaunchKernelGGL(kA, dim3(NB * NN), dim3(64), 0, stream,
                     h, Wdh, Wew, Wsa, u, v, e1, e2, s1, s2);
  hipLaunchKernelGGL(kB, dim3(NB * NN), dim3(256), 0, stream,
                     x, mask, mu, Wf, bf, bdh, Wew, bew, Wcm1, bcm1, Wcm2, bcm2,
                     u, v, s1, s2, e1, e2, hga, attn, out);
  hipLaunchKernelGGL(kC, dim3(NB * NN), dim3(64), 0, stream,
                     h, attn, hga, Wpn1, bpn1, Wpn2, bpn2, Wnm1, bnm1, Wnm2, bnm2, out);
}